// Round 1
// baseline (3340.486 us; speedup 1.0000x reference)
//
#include <hip/hip_runtime.h>

constexpr int UNITS = 10;
constexpr int TIN = 50;
constexpr int TOUT = 3;
constexpr int G4 = 4 * UNITS;   // 40 gates pre-activations

__device__ __forceinline__ float sigmoidf_(float x) {
    // 1/(1+exp(-x)) via v_exp_f32 + v_rcp_f32; |err| ~few ulp, OK vs 6.4e-5 abs threshold
    return __fdividef(1.0f, 1.0f + __expf(-x));
}

__global__ __launch_bounds__(256) void lstm_ae_kernel(
    const float* __restrict__ X,
    const float* __restrict__ W1, const float* __restrict__ R1, const float* __restrict__ b1,
    const float* __restrict__ W2, const float* __restrict__ R2, const float* __restrict__ b2,
    const float* __restrict__ Wd, const float* __restrict__ bd,
    float* __restrict__ out, int B)
{
    // All weights staged to LDS once per block; uniform-address reads broadcast (conflict-free).
    __shared__ float s[1344];
    float* sR1 = s;          // 400
    float* sR2 = s + 400;    // 400
    float* sW2 = s + 800;    // 400
    float* sW1 = s + 1200;   // 40
    float* sb1 = s + 1240;   // 40
    float* sb2 = s + 1280;   // 40
    float* sWd = s + 1320;   // 10
    float* sbd = s + 1336;   // 1

    for (int i = threadIdx.x; i < 400; i += 256) {
        sR1[i] = R1[i];
        sR2[i] = R2[i];
        sW2[i] = W2[i];
    }
    if (threadIdx.x < G4) {
        sW1[threadIdx.x] = W1[threadIdx.x];
        sb1[threadIdx.x] = b1[threadIdx.x];
        sb2[threadIdx.x] = b2[threadIdx.x];
    }
    if (threadIdx.x < UNITS) sWd[threadIdx.x] = Wd[threadIdx.x];
    if (threadIdx.x == 0) sbd[0] = bd[0];
    __syncthreads();

    const int b = blockIdx.x * blockDim.x + threadIdx.x;
    if (b >= B) return;

    const float* __restrict__ xrow = X + (size_t)b * TIN;

    // ---------------- LSTM 1: 50 steps, input dim 1 ----------------
    float h[UNITS], c[UNITS];
    #pragma unroll
    for (int u = 0; u < UNITS; ++u) { h[u] = 0.0f; c[u] = 0.0f; }

    #pragma unroll 1   // keep body (~5KB) inside I-cache
    for (int t = 0; t < TIN; ++t) {
        const float x = xrow[t];
        float z[G4];
        #pragma unroll
        for (int g = 0; g < G4; ++g) z[g] = fmaf(x, sW1[g], sb1[g]);
        #pragma unroll
        for (int u = 0; u < UNITS; ++u) {
            const float hu = h[u];
            #pragma unroll
            for (int g = 0; g < G4; ++g) z[g] = fmaf(hu, sR1[u * G4 + g], z[g]);
        }
        // gate order i, f, c(g), o
        #pragma unroll
        for (int u = 0; u < UNITS; ++u) {
            const float ig = sigmoidf_(z[u]);
            const float fg = sigmoidf_(z[UNITS + u]);
            const float gg = fmaxf(z[2 * UNITS + u], 0.0f);   // candidate act = relu
            const float og = sigmoidf_(z[3 * UNITS + u]);
            const float cn = fmaf(fg, c[u], ig * gg);
            c[u] = cn;
            h[u] = og * fmaxf(cn, 0.0f);                      // output act = relu
        }
    }

    // ---------------- RepeatVector(3) + LSTM 2 (3 steps) ----------------
    // Input to every step is the same h -> precompute xz2 = h @ W2 + b2 once.
    float xz2[G4];
    #pragma unroll
    for (int g = 0; g < G4; ++g) {
        float a = 0.0f;
        #pragma unroll
        for (int u = 0; u < UNITS; ++u) a = fmaf(h[u], sW2[u * G4 + g], a);
        xz2[g] = a + sb2[g];
    }

    float h2[UNITS], c2[UNITS];
    float* o3 = out + (size_t)b * TOUT;

    // t2 = 0: h2_prev = 0, c2_prev = 0 -> z = xz2, c = i*g
    {
        float acc = sbd[0];
        #pragma unroll
        for (int u = 0; u < UNITS; ++u) {
            const float ig = sigmoidf_(xz2[u]);
            const float gg = fmaxf(xz2[2 * UNITS + u], 0.0f);
            const float og = sigmoidf_(xz2[3 * UNITS + u]);
            const float cn = ig * gg;
            c2[u] = cn;
            const float hn = og * fmaxf(cn, 0.0f);
            h2[u] = hn;
            acc = fmaf(hn, sWd[u], acc);   // TimeDistributed Dense(1)
        }
        o3[0] = acc;
    }

    // t2 = 1,2: per-output-unit formulation keeps register pressure low
    #pragma unroll
    for (int t2 = 1; t2 < TOUT; ++t2) {
        float hold[UNITS];
        #pragma unroll
        for (int u = 0; u < UNITS; ++u) hold[u] = h2[u];
        float acc = sbd[0];
        #pragma unroll
        for (int u = 0; u < UNITS; ++u) {
            float zi = xz2[u];
            float zf = xz2[UNITS + u];
            float zg = xz2[2 * UNITS + u];
            float zo = xz2[3 * UNITS + u];
            #pragma unroll
            for (int v = 0; v < UNITS; ++v) {
                const float hv = hold[v];
                zi = fmaf(hv, sR2[v * G4 + u], zi);
                zf = fmaf(hv, sR2[v * G4 + UNITS + u], zf);
                zg = fmaf(hv, sR2[v * G4 + 2 * UNITS + u], zg);
                zo = fmaf(hv, sR2[v * G4 + 3 * UNITS + u], zo);
            }
            const float ig = sigmoidf_(zi);
            const float fg = sigmoidf_(zf);
            const float gg = fmaxf(zg, 0.0f);
            const float og = sigmoidf_(zo);
            const float cn = fmaf(fg, c2[u], ig * gg);
            c2[u] = cn;
            const float hn = og * fmaxf(cn, 0.0f);
            h2[u] = hn;
            acc = fmaf(hn, sWd[u], acc);
        }
        o3[t2] = acc;
    }
}

extern "C" void kernel_launch(void* const* d_in, const int* in_sizes, int n_in,
                              void* d_out, int out_size, void* d_ws, size_t ws_size,
                              hipStream_t stream) {
    const float* X  = (const float*)d_in[0];
    const float* W1 = (const float*)d_in[1];
    const float* R1 = (const float*)d_in[2];
    const float* b1 = (const float*)d_in[3];
    const float* W2 = (const float*)d_in[4];
    const float* R2 = (const float*)d_in[5];
    const float* b2 = (const float*)d_in[6];
    const float* Wd = (const float*)d_in[7];
    const float* bd = (const float*)d_in[8];
    float* out = (float*)d_out;

    const int B = in_sizes[0] / TIN;   // 524288
    const int block = 256;
    const int grid = (B + block - 1) / block;
    lstm_ae_kernel<<<grid, block, 0, stream>>>(X, W1, R1, b1, W2, R2, b2, Wd, bd, out, B);
}

// Round 2
// 867.153 us; speedup vs baseline: 3.8522x; 3.8522x over previous
//
#include <hip/hip_runtime.h>

constexpr int UNITS = 10;
constexpr int TIN = 50;
constexpr int TOUT = 3;
constexpr int G4 = 4 * UNITS;   // 40 gate pre-activations
constexpr int BLK = 256;

__device__ __forceinline__ float sigmoidf_(float x) {
    // v_exp_f32 + v_rcp_f32 (~1 ulp each) -> plenty vs 6.4e-5 abs threshold
    return __builtin_amdgcn_rcpf(1.0f + __expf(-x));
}

__global__ __launch_bounds__(BLK, 3) void lstm_ae_kernel(
    const float* __restrict__ X,
    const float* __restrict__ W1, const float* __restrict__ R1, const float* __restrict__ b1,
    const float* __restrict__ W2, const float* __restrict__ R2, const float* __restrict__ b2,
    const float* __restrict__ Wd, const float* __restrict__ bd,
    float* __restrict__ out, int B)
{
    // ---- Stage this block's X slice into LDS with coalesced float4 loads ----
    // Rows handled by this block are contiguous in X: [blockIdx.x*BLK*TIN, ...)
    __shared__ float xs[BLK * TIN];            // 51.2 KB -> 3 blocks/CU
    {
        const size_t basef = (size_t)blockIdx.x * BLK * TIN;   // in floats
        const size_t totalf = (size_t)B * TIN;
        const float4* __restrict__ src = (const float4*)(X + basef);
        float4* dst = (float4*)xs;
        constexpr int N4 = BLK * TIN / 4;      // 3200
        #pragma unroll
        for (int i = 0; i < (N4 + BLK - 1) / BLK; ++i) {
            const int idx = threadIdx.x + i * BLK;
            if (idx < N4 && basef + (size_t)idx * 4 < totalf) dst[idx] = src[idx];
        }
    }
    __syncthreads();

    const int b = blockIdx.x * BLK + threadIdx.x;
    if (b >= B) return;
    const float* __restrict__ xrow = xs + threadIdx.x * TIN;

    // ---------------- LSTM 1: 50 steps, input dim 1 ----------------
    // Weights are read straight from global with uniform (compile-time) indices:
    // the compiler scalarizes these to s_load -> scalar K$, off the VALU/LDS pipes.
    float h[UNITS], c[UNITS];
    #pragma unroll
    for (int u = 0; u < UNITS; ++u) { h[u] = 0.0f; c[u] = 0.0f; }

    #pragma unroll 1   // keep the ~1.5k-instr body inside I-cache
    for (int t = 0; t < TIN; ++t) {
        const float x = xrow[t];
        float z[G4];
        #pragma unroll
        for (int g = 0; g < G4; ++g) z[g] = fmaf(x, W1[g], b1[g]);
        #pragma unroll
        for (int u = 0; u < UNITS; ++u) {
            const float hu = h[u];
            #pragma unroll
            for (int g = 0; g < G4; ++g) z[g] = fmaf(hu, R1[u * G4 + g], z[g]);
        }
        // gate order i, f, c(g), o
        #pragma unroll
        for (int u = 0; u < UNITS; ++u) {
            const float ig = sigmoidf_(z[u]);
            const float fg = sigmoidf_(z[UNITS + u]);
            const float gg = fmaxf(z[2 * UNITS + u], 0.0f);   // candidate act = relu
            const float og = sigmoidf_(z[3 * UNITS + u]);
            const float cn = fmaf(fg, c[u], ig * gg);
            c[u] = cn;
            h[u] = og * fmaxf(cn, 0.0f);                      // output act = relu
        }
    }

    // ---------------- RepeatVector(3) + LSTM 2 (3 steps) ----------------
    // Same input h every step -> precompute xz2 = h @ W2 + b2 once.
    float xz2[G4];
    #pragma unroll
    for (int g = 0; g < G4; ++g) {
        float a = b2[g];
        #pragma unroll
        for (int u = 0; u < UNITS; ++u) a = fmaf(h[u], W2[u * G4 + g], a);
        xz2[g] = a;
    }

    float h2[UNITS], c2[UNITS];
    float o0, o1, o2;

    // t2 = 0: h_prev = c_prev = 0 -> z = xz2, c = i*g
    {
        float acc = bd[0];
        #pragma unroll
        for (int u = 0; u < UNITS; ++u) {
            const float ig = sigmoidf_(xz2[u]);
            const float gg = fmaxf(xz2[2 * UNITS + u], 0.0f);
            const float og = sigmoidf_(xz2[3 * UNITS + u]);
            const float cn = ig * gg;
            c2[u] = cn;
            const float hn = og * fmaxf(cn, 0.0f);
            h2[u] = hn;
            acc = fmaf(hn, Wd[u], acc);        // TimeDistributed Dense(1)
        }
        o0 = acc;
    }

    // t2 = 1, 2 — per-output-unit formulation keeps live-register count low
    float oacc[2];
    #pragma unroll
    for (int t2 = 0; t2 < 2; ++t2) {
        float hold[UNITS];
        #pragma unroll
        for (int u = 0; u < UNITS; ++u) hold[u] = h2[u];
        float acc = bd[0];
        #pragma unroll
        for (int u = 0; u < UNITS; ++u) {
            float zi = xz2[u];
            float zf = xz2[UNITS + u];
            float zg = xz2[2 * UNITS + u];
            float zo = xz2[3 * UNITS + u];
            #pragma unroll
            for (int v = 0; v < UNITS; ++v) {
                const float hv = hold[v];
                zi = fmaf(hv, R2[v * G4 + u], zi);
                zf = fmaf(hv, R2[v * G4 + UNITS + u], zf);
                zg = fmaf(hv, R2[v * G4 + 2 * UNITS + u], zg);
                zo = fmaf(hv, R2[v * G4 + 3 * UNITS + u], zo);
            }
            const float ig = sigmoidf_(zi);
            const float fg = sigmoidf_(zf);
            const float gg = fmaxf(zg, 0.0f);
            const float og = sigmoidf_(zo);
            const float cn = fmaf(fg, c2[u], ig * gg);
            c2[u] = cn;
            const float hn = og * fmaxf(cn, 0.0f);
            h2[u] = hn;
            acc = fmaf(hn, Wd[u], acc);
        }
        oacc[t2] = acc;
    }
    o1 = oacc[0];
    o2 = oacc[1];

    float* __restrict__ o3 = out + (size_t)b * TOUT;
    o3[0] = o0;
    o3[1] = o1;
    o3[2] = o2;
}

extern "C" void kernel_launch(void* const* d_in, const int* in_sizes, int n_in,
                              void* d_out, int out_size, void* d_ws, size_t ws_size,
                              hipStream_t stream) {
    const float* X  = (const float*)d_in[0];
    const float* W1 = (const float*)d_in[1];
    const float* R1 = (const float*)d_in[2];
    const float* b1 = (const float*)d_in[3];
    const float* W2 = (const float*)d_in[4];
    const float* R2 = (const float*)d_in[5];
    const float* b2 = (const float*)d_in[6];
    const float* Wd = (const float*)d_in[7];
    const float* bd = (const float*)d_in[8];
    float* out = (float*)d_out;

    const int B = in_sizes[0] / TIN;   // 524288
    const int grid = (B + BLK - 1) / BLK;
    lstm_ae_kernel<<<grid, BLK, 0, stream>>>(X, W1, R1, b1, W2, R2, b2, Wd, bd, out, B);
}